// Round 1
// baseline (2222.097 us; speedup 1.0000x reference)
//
#include <hip/hip_runtime.h>

// VectorQuantizer: N=32768 tokens, K=8192 codes, D=256, fp32.
// Outputs (concat, float): z_q_ste[32768*256], idx[32768] (as float), loss[1].
// argmin_c ||x-c||^2 == argmin_c (||c||^2 - 2 x.c)  (per-token ||x||^2 constant dropped)

#define N_TOK   32768
#define KC      8192
#define DD      256
#define D4      (DD/4)
#define SPLITS  8
#define KSPLIT  (KC/SPLITS)     // 1024 codes per split
#define TM      64              // tokens per block
#define TN      128             // codes per chunk
#define BK      32              // d-slice
#define NCHUNK  (KSPLIT/TN)     // 8
#define NKS     (DD/BK)         // 8
#define XS_STRIDE (TM+4)        // 68 floats: keeps 16B alignment for b128 reads
#define CS_STRIDE (TN+4)        // 132 floats

// ---------------- kernel 1: code norms + zero loss accumulator ----------------
__global__ __launch_bounds__(256)
void k_cnorm(const float* __restrict__ cb, float* __restrict__ cnorm,
             double* __restrict__ accum) {
    if (blockIdx.x == 0 && threadIdx.x == 0) *accum = 0.0;  // ws is poisoned 0xAA each call
    const int gid  = blockIdx.x * 256 + threadIdx.x;
    const int code = gid >> 6;          // one wave (64 lanes) per code
    const int lane = threadIdx.x & 63;
    if (code < KC) {
        float4 v = ((const float4*)cb)[code * D4 + lane];   // 64 lanes x 16B = one 1KB row
        float s = v.x*v.x + v.y*v.y + v.z*v.z + v.w*v.w;
        #pragma unroll
        for (int off = 32; off > 0; off >>= 1) s += __shfl_down(s, off);
        if (lane == 0) cnorm[code] = s;
    }
}

// ---------------- kernel 2: distance GEMM + running argmin (per code-split) ----------------
__global__ __launch_bounds__(128)
void k_argmin(const float* __restrict__ ze, const float* __restrict__ cb,
              const float* __restrict__ cnorm, float2* __restrict__ partial) {
    // grid: (N_TOK/TM, SPLITS), block: 128 threads = (tx 0..15 codes) x (ty 0..7 tokens)
    // thread micro-tile: 8 tokens x 8 codes
    __shared__ __align__(16) float smem[BK*XS_STRIDE + BK*CS_STRIDE];
    float* xs = smem;                       // [BK][XS_STRIDE]  transposed: [d][token]
    float* cs = smem + BK*XS_STRIDE;        // [BK][CS_STRIDE]  transposed: [d][code]

    const int tid = threadIdx.x;
    const int tx  = tid & 15;
    const int ty  = tid >> 4;
    const int m0  = blockIdx.x * TM;
    const int s   = blockIdx.y;

    float bestv[8];
    int   besti[8];
    #pragma unroll
    for (int r = 0; r < 8; ++r) { bestv[r] = 3.4e38f; besti[r] = 0; }

    for (int ch = 0; ch < NCHUNK; ++ch) {
        const int c0 = s * KSPLIT + ch * TN;
        float acc[8][8];
        #pragma unroll
        for (int r = 0; r < 8; ++r)
            #pragma unroll
            for (int c = 0; c < 8; ++c) acc[r][c] = 0.f;

        for (int ks = 0; ks < NKS; ++ks) {
            __syncthreads();   // protect previous slice's readers
            // stage x slice: 64 rows x 32 d = 512 float4, 4 per thread (coalesced)
            #pragma unroll
            for (int i = 0; i < 4; ++i) {
                int f = tid + i * 128;
                int row = f >> 3, dg = f & 7;
                float4 v = *(const float4*)(ze + (m0 + row) * DD + ks * BK + dg * 4);
                int d0 = dg * 4;
                xs[(d0+0)*XS_STRIDE + row] = v.x;
                xs[(d0+1)*XS_STRIDE + row] = v.y;
                xs[(d0+2)*XS_STRIDE + row] = v.z;
                xs[(d0+3)*XS_STRIDE + row] = v.w;
            }
            // stage c slice: 128 rows x 32 d = 1024 float4, 8 per thread (coalesced)
            #pragma unroll
            for (int i = 0; i < 8; ++i) {
                int f = tid + i * 128;
                int row = f >> 3, dg = f & 7;
                float4 v = *(const float4*)(cb + (c0 + row) * DD + ks * BK + dg * 4);
                int d0 = dg * 4;
                cs[(d0+0)*CS_STRIDE + row] = v.x;
                cs[(d0+1)*CS_STRIDE + row] = v.y;
                cs[(d0+2)*CS_STRIDE + row] = v.z;
                cs[(d0+3)*CS_STRIDE + row] = v.w;
            }
            __syncthreads();
            #pragma unroll 4
            for (int d = 0; d < BK; ++d) {
                float4 xa0 = *(const float4*)(xs + d * XS_STRIDE + ty * 8);
                float4 xa1 = *(const float4*)(xs + d * XS_STRIDE + ty * 8 + 4);
                float4 ca0 = *(const float4*)(cs + d * CS_STRIDE + tx * 8);
                float4 ca1 = *(const float4*)(cs + d * CS_STRIDE + tx * 8 + 4);
                float xv[8] = {xa0.x, xa0.y, xa0.z, xa0.w, xa1.x, xa1.y, xa1.z, xa1.w};
                float cv[8] = {ca0.x, ca0.y, ca0.z, ca0.w, ca1.x, ca1.y, ca1.z, ca1.w};
                #pragma unroll
                for (int r = 0; r < 8; ++r)
                    #pragma unroll
                    for (int c = 0; c < 8; ++c)
                        acc[r][c] = fmaf(xv[r], cv[c], acc[r][c]);
            }
        }
        // fold chunk into running argmin; in-thread code order is ascending so
        // strict '<' keeps the first (lowest-index) minimum, matching jnp.argmin.
        #pragma unroll
        for (int c = 0; c < 8; ++c) {
            const int code = c0 + tx * 8 + c;
            const float cn = cnorm[code];
            #pragma unroll
            for (int r = 0; r < 8; ++r) {
                float dist = fmaf(-2.f, acc[r][c], cn);
                if (dist < bestv[r]) { bestv[r] = dist; besti[r] = code; }
            }
        }
    }

    // cross-thread (tx) reduction per token; reuse smem (all tile reads are done)
    __syncthreads();
    float2* red = (float2*)smem;    // [TM][16]
    #pragma unroll
    for (int r = 0; r < 8; ++r)
        red[(ty * 8 + r) * 16 + tx] = make_float2(bestv[r], __int_as_float(besti[r]));
    __syncthreads();
    if (tid < TM) {
        float bv = red[tid * 16].x;
        int   bi = __float_as_int(red[tid * 16].y);
        #pragma unroll
        for (int j = 1; j < 16; ++j) {
            float2 p = red[tid * 16 + j];
            int ii = __float_as_int(p.y);
            if (p.x < bv || (p.x == bv && ii < bi)) { bv = p.x; bi = ii; }
        }
        partial[s * N_TOK + m0 + tid] = make_float2(bv, __int_as_float(bi));
    }
}

// ---------------- kernel 3: combine code-splits ----------------
__global__ __launch_bounds__(256)
void k_combine(const float2* __restrict__ partial, int* __restrict__ idxi,
               float* __restrict__ idxf) {
    const int t = blockIdx.x * 256 + threadIdx.x;
    float bv = 3.4e38f; int bi = 0;
    #pragma unroll
    for (int s = 0; s < SPLITS; ++s) {   // splits ascend in code index -> ties keep first
        float2 p = partial[s * N_TOK + t];
        int ii = __float_as_int(p.y);
        if (p.x < bv || (p.x == bv && ii < bi)) { bv = p.x; bi = ii; }
    }
    idxi[t] = bi;
    idxf[t] = (float)bi;
}

// ---------------- kernel 4: gather + STE output + loss partial ----------------
__global__ __launch_bounds__(256)
void k_gather(const float* __restrict__ ze, const float* __restrict__ cb,
              const int* __restrict__ idxi, float* __restrict__ zq,
              double* __restrict__ accum) {
    const int tid = threadIdx.x;
    const int t0  = blockIdx.x * 16;    // 16 tokens per block, 4 float4 per thread
    double dsum = 0.0;
    #pragma unroll
    for (int i = 0; i < 4; ++i) {
        int f = tid + i * 256;
        int row = f >> 6, e = f & 63;
        int t = t0 + row;
        int code = idxi[t];
        float4 zev = ((const float4*)ze)[t * D4 + e];
        float4 cbv = ((const float4*)cb)[code * D4 + e];
        float dx = cbv.x - zev.x, dy = cbv.y - zev.y;
        float dz = cbv.z - zev.z, dw = cbv.w - zev.w;
        float4 o;                        // z_e + (z_q - z_e): matches reference rounding
        o.x = zev.x + dx; o.y = zev.y + dy; o.z = zev.z + dz; o.w = zev.w + dw;
        ((float4*)zq)[t * D4 + e] = o;
        dsum += (double)dx * dx + (double)dy * dy + (double)dz * dz + (double)dw * dw;
    }
    #pragma unroll
    for (int off = 32; off > 0; off >>= 1) dsum += __shfl_down(dsum, off);
    __shared__ double wsum[4];
    if ((tid & 63) == 0) wsum[tid >> 6] = dsum;
    __syncthreads();
    if (tid == 0) atomicAdd(accum, wsum[0] + wsum[1] + wsum[2] + wsum[3]);
}

// ---------------- kernel 5: finalize loss ----------------
__global__ void k_final(const double* __restrict__ accum, float* __restrict__ loss) {
    // codebook_loss + beta*commit_loss = (1+0.25) * mean((z_q - z_e)^2)
    loss[0] = (float)(accum[0] * (1.25 / 8388608.0));
}

extern "C" void kernel_launch(void* const* d_in, const int* in_sizes, int n_in,
                              void* d_out, int out_size, void* d_ws, size_t ws_size,
                              hipStream_t stream) {
    const float* ze = (const float*)d_in[0];    // (16,2048,256) -> (32768,256)
    const float* cb = (const float*)d_in[1];    // (8192,256)

    float* out      = (float*)d_out;
    float* out_zq   = out;                          // 8,388,608 floats
    float* out_idx  = out + (size_t)N_TOK * DD;     // 32,768 floats
    float* out_loss = out_idx + N_TOK;              // 1 float

    char*   ws    = (char*)d_ws;
    float*  cnorm = (float*)ws;                     // 32 KB
    int*    idxi  = (int*)(ws + 32768);             // 128 KB
    double* accum = (double*)(ws + 163840);         // 8 B
    const size_t part_off = 163848;
    const size_t need = part_off + (size_t)SPLITS * N_TOK * sizeof(float2);  // ~2.3 MB
    // partial (minval,idx) per split; fall back to the z_q output region (4 MB < 32 MB,
    // consumed by k_combine before k_gather overwrites it) if ws is too small.
    float2* partial = (ws_size >= need) ? (float2*)(ws + part_off) : (float2*)d_out;

    hipLaunchKernelGGL(k_cnorm,   dim3(KC / 4),        dim3(256), 0, stream, cb, cnorm, accum);
    hipLaunchKernelGGL(k_argmin,  dim3(N_TOK / TM, SPLITS), dim3(128), 0, stream, ze, cb, cnorm, partial);
    hipLaunchKernelGGL(k_combine, dim3(N_TOK / 256),   dim3(256), 0, stream, partial, idxi, out_idx);
    hipLaunchKernelGGL(k_gather,  dim3(N_TOK / 16),    dim3(256), 0, stream, ze, cb, idxi, out_zq, accum);
    hipLaunchKernelGGL(k_final,   dim3(1),             dim3(1),   0, stream, accum, out_loss);
}

// Round 2
// 888.762 us; speedup vs baseline: 2.5002x; 2.5002x over previous
//
#include <hip/hip_runtime.h>

// VectorQuantizer: N=32768 tokens, K=8192 codes, D=256, fp32 in/out.
// Outputs (concat, float): z_q_ste[32768*256], idx[32768] (as float), loss[1].
// argmin_c ||x-c||^2 == argmin_c (||c||^2 - 2 x.c).
// Strategy: bf16-split 3-term MFMA GEMM (hi*hi + hi*lo + lo*hi, fp32 acc),
// track per-token (best, idx, second); tokens with gap < EPS_GAP get an exact
// fp32 rescore over all codes (expected ~100 tokens).

#define N_TOK   32768
#define KC      8192
#define DD      256
#define D4      64              // DD/4
#define SPLITS  16
#define KSPLIT  512             // KC/SPLITS
#define MT      128             // tokens per block
#define NT      128             // codes per N-tile
#define BK      32
#define NTILES  4               // KSPLIT/NT
#define NKS     8               // DD/BK
#define ASTR    40              // LDS row stride in ushorts (32 + 8 pad, keeps 16B align)
#define EPS_GAP 1e-3f
#define FLAG_CAP 16384

typedef __bf16 bf16x8 __attribute__((ext_vector_type(8)));
typedef float  f32x4  __attribute__((ext_vector_type(4)));

// ---------------- kernel 1: code norms + zero accumulators ----------------
__global__ __launch_bounds__(256)
void k_cnorm(const float* __restrict__ cb, float* __restrict__ cnorm,
             double* __restrict__ accum, int* __restrict__ flagc) {
    if (blockIdx.x == 0 && threadIdx.x == 0) { *accum = 0.0; *flagc = 0; }
    const int gid  = blockIdx.x * 256 + threadIdx.x;
    const int code = gid >> 6;
    const int lane = threadIdx.x & 63;
    if (code < KC) {
        float4 v = ((const float4*)cb)[code * D4 + lane];
        float s = v.x*v.x + v.y*v.y + v.z*v.z + v.w*v.w;
        #pragma unroll
        for (int off = 32; off > 0; off >>= 1) s += __shfl_down(s, off);
        if (lane == 0) cnorm[code] = s;
    }
}

// float pair -> packed bf16 hi (truncated) and bf16 lo (truncated residual)
__device__ __forceinline__ void stage8(const float* __restrict__ gp,
                                       ushort* __restrict__ h, ushort* __restrict__ l) {
    float4 v0 = *(const float4*)gp;
    float4 v1 = *(const float4*)(gp + 4);
    uint4 hp, lp;
    #define PK(a, b, HO, LO) do {                                   \
        unsigned ua = __float_as_uint(a), ub = __float_as_uint(b);  \
        unsigned ham = ua & 0xFFFF0000u, hbm = ub & 0xFFFF0000u;    \
        float la = (a) - __uint_as_float(ham);                      \
        float lb = (b) - __uint_as_float(hbm);                      \
        HO = (ua >> 16) | hbm;                                      \
        LO = (__float_as_uint(la) >> 16) | (__float_as_uint(lb) & 0xFFFF0000u); \
    } while (0)
    PK(v0.x, v0.y, hp.x, lp.x);
    PK(v0.z, v0.w, hp.y, lp.y);
    PK(v1.x, v1.y, hp.z, lp.z);
    PK(v1.z, v1.w, hp.w, lp.w);
    #undef PK
    *(uint4*)h = hp;
    *(uint4*)l = lp;
}

// ---------------- kernel 2: 3-term bf16 MFMA GEMM + top-2 argmin ----------------
__global__ __launch_bounds__(256, 2)
void k_argmin_mfma(const float* __restrict__ ze, const float* __restrict__ cb,
                   const float* __restrict__ cnorm, float4* __restrict__ partial) {
    __shared__ ushort smem[4 * 128 * ASTR];       // Ah, Al, Bh, Bl: 40 KB
    ushort* Ah = smem;
    ushort* Al = smem + 128 * ASTR;
    ushort* Bh = smem + 2 * 128 * ASTR;
    ushort* Bl = smem + 3 * 128 * ASTR;

    const int tid  = threadIdx.x;
    const int lane = tid & 63;
    const int wid  = tid >> 6;
    const int cl   = lane & 15;       // col within 16x16 (also A/B row for frags)
    const int kq   = lane >> 4;       // k-quad
    const int wm   = (wid & 1) * 64;
    const int wn   = (wid >> 1) * 64;
    const int m0   = blockIdx.x * MT;
    const int split = blockIdx.y;

    // staging assignment: i = tid (+256), row = i>>2 (0..127), 8-float group g = (i&3)*8
    const int r0 = tid >> 2;
    const int g0 = (tid & 3) * 8;
    const float* zeA   = ze + (size_t)(m0 + r0) * DD + g0;
    ushort* lAh0 = Ah + r0 * ASTR + g0;
    ushort* lAl0 = Al + r0 * ASTR + g0;
    ushort* lAh1 = Ah + (r0 + 64) * ASTR + g0;
    ushort* lAl1 = Al + (r0 + 64) * ASTR + g0;
    ushort* lBh0 = Bh + r0 * ASTR + g0;
    ushort* lBl0 = Bl + r0 * ASTR + g0;
    ushort* lBh1 = Bh + (r0 + 64) * ASTR + g0;
    ushort* lBl1 = Bl + (r0 + 64) * ASTR + g0;

    const int aoff = (wm + cl) * ASTR + kq * 8;
    const int boff = (wn + cl) * ASTR + kq * 8;

    float best[16], sec[16]; int bidx[16];
    #pragma unroll
    for (int s = 0; s < 16; ++s) { best[s] = 3.4e38f; sec[s] = 3.4e38f; bidx[s] = 0; }

    for (int ch = 0; ch < NTILES; ++ch) {
        const int c0 = split * KSPLIT + ch * NT;
        const float* cbB = cb + (size_t)(c0 + r0) * DD + g0;
        f32x4 acc[4][4];
        #pragma unroll
        for (int mt = 0; mt < 4; ++mt)
            #pragma unroll
            for (int nt = 0; nt < 4; ++nt)
                acc[mt][nt] = (f32x4){0.f, 0.f, 0.f, 0.f};

        for (int ks = 0; ks < NKS; ++ks) {
            __syncthreads();
            stage8(zeA + ks * BK,            lAh0, lAl0);
            stage8(zeA + 64 * DD + ks * BK,  lAh1, lAl1);
            stage8(cbB + ks * BK,            lBh0, lBl0);
            stage8(cbB + 64 * DD + ks * BK,  lBh1, lBl1);
            __syncthreads();

            bf16x8 bh[4], bl[4];
            #pragma unroll
            for (int nt = 0; nt < 4; ++nt) {
                bh[nt] = *(const bf16x8*)(Bh + boff + nt * 16 * ASTR);
                bl[nt] = *(const bf16x8*)(Bl + boff + nt * 16 * ASTR);
            }
            #pragma unroll
            for (int mt = 0; mt < 4; ++mt) {
                bf16x8 ah = *(const bf16x8*)(Ah + aoff + mt * 16 * ASTR);
                bf16x8 al = *(const bf16x8*)(Al + aoff + mt * 16 * ASTR);
                #pragma unroll
                for (int nt = 0; nt < 4; ++nt) {
                    acc[mt][nt] = __builtin_amdgcn_mfma_f32_16x16x32_bf16(ah, bh[nt], acc[mt][nt], 0, 0, 0);
                    acc[mt][nt] = __builtin_amdgcn_mfma_f32_16x16x32_bf16(ah, bl[nt], acc[mt][nt], 0, 0, 0);
                    acc[mt][nt] = __builtin_amdgcn_mfma_f32_16x16x32_bf16(al, bh[nt], acc[mt][nt], 0, 0, 0);
                }
            }
        }
        // fold this N-tile into running top-2 (codes ascend with ch,nt: '<' keeps first idx)
        #pragma unroll
        for (int nt = 0; nt < 4; ++nt) {
            const int code = c0 + wn + nt * 16 + cl;
            const float cn = cnorm[code];
            #pragma unroll
            for (int mt = 0; mt < 4; ++mt)
                #pragma unroll
                for (int r = 0; r < 4; ++r) {
                    float dist = fmaf(-2.f, acc[mt][nt][r], cn);
                    int s = mt * 4 + r;
                    bool lt = dist < best[s];
                    sec[s] = lt ? best[s] : fminf(sec[s], dist);
                    if (lt) { best[s] = dist; bidx[s] = code; }
                }
        }
    }

    // cross-lane reduce over the 16 col-lanes (masks 1,2,4,8 stay in 16-lane group)
    #pragma unroll
    for (int m = 1; m < 16; m <<= 1) {
        #pragma unroll
        for (int s = 0; s < 16; ++s) {
            float ob = __shfl_xor(best[s], m);
            int   oi = __shfl_xor(bidx[s], m);
            float os = __shfl_xor(sec[s], m);
            if (ob < best[s] || (ob == best[s] && oi < bidx[s])) {
                sec[s]  = fminf(best[s], os);
                best[s] = ob; bidx[s] = oi;
            } else {
                sec[s]  = fminf(sec[s], ob);
            }
        }
    }
    __syncthreads();
    float* mg = (float*)smem;                 // [2][128][4] floats = 4 KB (reuse LDS)
    if (cl == 0) {
        #pragma unroll
        for (int mt = 0; mt < 4; ++mt)
            #pragma unroll
            for (int r = 0; r < 4; ++r) {
                int row = wm + mt * 16 + kq * 4 + r;
                int o = ((wn >> 6) * 128 + row) * 4;
                mg[o + 0] = best[mt * 4 + r];
                mg[o + 1] = __int_as_float(bidx[mt * 4 + r]);
                mg[o + 2] = sec[mt * 4 + r];
            }
    }
    __syncthreads();
    if (tid < MT) {
        float b0 = mg[tid * 4],         s0v = mg[tid * 4 + 2];
        int   i0 = __float_as_int(mg[tid * 4 + 1]);
        float b1 = mg[(128 + tid) * 4], s1v = mg[(128 + tid) * 4 + 2];
        int   i1 = __float_as_int(mg[(128 + tid) * 4 + 1]);
        float B, S; int I;
        if (b1 < b0 || (b1 == b0 && i1 < i0)) { B = b1; I = i1; S = fminf(s1v, b0); }
        else                                   { B = b0; I = i0; S = fminf(s0v, b1); }
        partial[(size_t)split * N_TOK + m0 + tid] = make_float4(B, __int_as_float(I), S, 0.f);
    }
}

// ---------------- kernel 3: combine splits, emit idx + rescore flags ----------------
__global__ __launch_bounds__(256)
void k_combine(const float4* __restrict__ partial, int* __restrict__ idxi,
               float* __restrict__ idxf, int* __restrict__ flagc,
               int* __restrict__ flag_list) {
    const int t = blockIdx.x * 256 + threadIdx.x;
    float B = 3.4e38f, S = 3.4e38f; int I = 0;
    #pragma unroll
    for (int s = 0; s < SPLITS; ++s) {
        float4 p = partial[(size_t)s * N_TOK + t];
        int oi = __float_as_int(p.y);
        if (p.x < B || (p.x == B && oi < I)) { S = fminf(B, p.z); B = p.x; I = oi; }
        else                                  { S = fminf(S, p.x); }
    }
    idxi[t] = I;
    idxf[t] = (float)I;
    if (S - B < EPS_GAP) {
        int pos = atomicAdd(flagc, 1);
        if (pos < FLAG_CAP) flag_list[pos] = t;
    }
}

// ---------------- kernel 4: exact fp32 rescore for flagged tokens ----------------
__global__ __launch_bounds__(256)
void k_rescore(const float* __restrict__ ze, const float* __restrict__ cb,
               const float* __restrict__ cnorm, const int* __restrict__ flagc,
               const int* __restrict__ flag_list, int* __restrict__ idxi,
               float* __restrict__ idxf) {
    __shared__ float xsh[DD];
    __shared__ float2 red[256];
    const int tid = threadIdx.x;
    int nf = flagc[0]; if (nf > FLAG_CAP) nf = FLAG_CAP;
    for (int f = blockIdx.x; f < nf; f += gridDim.x) {
        const int t = flag_list[f];
        if (tid < 64) *(float4*)&xsh[tid * 4] = ((const float4*)ze)[(size_t)t * D4 + tid];
        __syncthreads();
        float B = 3.4e38f; int I = 0;
        for (int c = tid; c < KC; c += 256) {
            const float4* cr = (const float4*)(cb + (size_t)c * DD);
            float dot = 0.f;
            #pragma unroll 8
            for (int j = 0; j < D4; ++j) {
                float4 cv = cr[j];
                float4 xv = *(const float4*)&xsh[j * 4];
                dot = fmaf(cv.x, xv.x, dot);
                dot = fmaf(cv.y, xv.y, dot);
                dot = fmaf(cv.z, xv.z, dot);
                dot = fmaf(cv.w, xv.w, dot);
            }
            float dist = fmaf(-2.f, dot, cnorm[c]);
            if (dist < B) { B = dist; I = c; }       // c ascends: first-min kept
        }
        red[tid] = make_float2(B, __int_as_float(I));
        __syncthreads();
        for (int s = 128; s > 0; s >>= 1) {
            if (tid < s) {
                float2 o = red[tid + s], me = red[tid];
                int oi = __float_as_int(o.y), mi = __float_as_int(me.y);
                if (o.x < me.x || (o.x == me.x && oi < mi)) red[tid] = o;
            }
            __syncthreads();
        }
        if (tid == 0) { int I2 = __float_as_int(red[0].y); idxi[t] = I2; idxf[t] = (float)I2; }
        __syncthreads();
    }
}

// ---------------- kernel 5: gather + STE output + loss partial ----------------
__global__ __launch_bounds__(256)
void k_gather(const float* __restrict__ ze, const float* __restrict__ cb,
              const int* __restrict__ idxi, float* __restrict__ zq,
              double* __restrict__ accum) {
    const int tid = threadIdx.x;
    const int t0  = blockIdx.x * 16;
    double dsum = 0.0;
    #pragma unroll
    for (int i = 0; i < 4; ++i) {
        int f = tid + i * 256;
        int row = f >> 6, e = f & 63;
        int t = t0 + row;
        int code = idxi[t];
        float4 zev = ((const float4*)ze)[(size_t)t * D4 + e];
        float4 cbv = ((const float4*)cb)[(size_t)code * D4 + e];
        float dx = cbv.x - zev.x, dy = cbv.y - zev.y;
        float dz = cbv.z - zev.z, dw = cbv.w - zev.w;
        float4 o;
        o.x = zev.x + dx; o.y = zev.y + dy; o.z = zev.z + dz; o.w = zev.w + dw;
        ((float4*)zq)[(size_t)t * D4 + e] = o;
        dsum += (double)dx * dx + (double)dy * dy + (double)dz * dz + (double)dw * dw;
    }
    #pragma unroll
    for (int off = 32; off > 0; off >>= 1) dsum += __shfl_down(dsum, off);
    __shared__ double wsum[4];
    if ((tid & 63) == 0) wsum[tid >> 6] = dsum;
    __syncthreads();
    if (tid == 0) atomicAdd(accum, wsum[0] + wsum[1] + wsum[2] + wsum[3]);
}

// ---------------- kernel 6: finalize loss ----------------
__global__ void k_final(const double* __restrict__ accum, float* __restrict__ loss) {
    loss[0] = (float)(accum[0] * (1.25 / 8388608.0));
}

extern "C" void kernel_launch(void* const* d_in, const int* in_sizes, int n_in,
                              void* d_out, int out_size, void* d_ws, size_t ws_size,
                              hipStream_t stream) {
    const float* ze = (const float*)d_in[0];
    const float* cb = (const float*)d_in[1];

    float* out      = (float*)d_out;
    float* out_zq   = out;
    float* out_idx  = out + (size_t)N_TOK * DD;
    float* out_loss = out_idx + N_TOK;

    char*   ws    = (char*)d_ws;
    float*  cnorm = (float*)ws;                     // 32 KB
    int*    idxi  = (int*)(ws + 32768);             // 128 KB
    double* accum = (double*)(ws + 163840);         // 8 B
    int*    flagc = (int*)(ws + 163848);            // 4 B
    const size_t big_off = 163856;
    const size_t need = big_off + (size_t)FLAG_CAP * 4 + (size_t)SPLITS * N_TOK * 16;
    int* flag_list; float4* partial;
    if (ws_size >= need) {
        flag_list = (int*)(ws + big_off);
        partial   = (float4*)(ws + big_off + (size_t)FLAG_CAP * 4);
    } else {
        // fall back to the z_q output region (33.5 MB): partial (8 MB) + list (64 KB),
        // both fully consumed before k_gather overwrites z_q.
        partial   = (float4*)d_out;
        flag_list = (int*)((char*)d_out + (size_t)SPLITS * N_TOK * 16);
    }

    hipLaunchKernelGGL(k_cnorm,       dim3(KC / 4),            dim3(256), 0, stream, cb, cnorm, accum, flagc);
    hipLaunchKernelGGL(k_argmin_mfma, dim3(N_TOK / MT, SPLITS), dim3(256), 0, stream, ze, cb, cnorm, partial);
    hipLaunchKernelGGL(k_combine,     dim3(N_TOK / 256),       dim3(256), 0, stream, partial, idxi, out_idx, flagc, flag_list);
    hipLaunchKernelGGL(k_rescore,     dim3(128),               dim3(256), 0, stream, ze, cb, cnorm, flagc, flag_list, idxi, out_idx);
    hipLaunchKernelGGL(k_gather,      dim3(N_TOK / 16),        dim3(256), 0, stream, ze, cb, idxi, out_zq, accum);
    hipLaunchKernelGGL(k_final,       dim3(1),                 dim3(1),   0, stream, accum, out_loss);
}

// Round 3
// 818.224 us; speedup vs baseline: 2.7158x; 1.0862x over previous
//
#include <hip/hip_runtime.h>

// VectorQuantizer: N=32768 tokens, K=8192 codes, D=256, fp32 in/out.
// Outputs (concat, float): z_q_ste[32768*256], idx[32768] (as float), loss[1].
// argmin_c ||x-c||^2 == argmin_c (||c||^2 - 2 x.c).
// R3: pre-convert fp32 -> bf16 hi/lo once (k_convert), then MFMA GEMM stages
// pre-packed bf16 via global_load_lds (async, zero staging VALU) with an XOR
// bank swizzle. MFMA math is bit-identical to R2's passing kernel.

#define N_TOK   32768
#define KC      8192
#define DD      256
#define D4      64
#define SPLITS  8
#define KSPLIT  1024
#define MT      128
#define NT      128
#define BK      32
#define NTILES  8               // KSPLIT/NT
#define NKS     8               // DD/BK
#define EPS_GAP 1e-3f
#define FLAG_CAP 16384

typedef __bf16 bf16x8 __attribute__((ext_vector_type(8)));
typedef float  f32x4  __attribute__((ext_vector_type(4)));

// async 16B global->LDS (lds dst must be wave-uniform; HW writes dst + lane*16)
#define GLL(gp, lp) __builtin_amdgcn_global_load_lds(                                   \
    (const __attribute__((address_space(1))) void*)(unsigned long long)(uintptr_t)(gp), \
    (__attribute__((address_space(3))) void*)(unsigned)(uintptr_t)(lp), 16, 0, 0)

// float pair -> packed bf16 hi (truncated) and bf16 lo (truncated residual)
#define PK(a, b, HO, LO) do {                                   \
    unsigned ua = __float_as_uint(a), ub = __float_as_uint(b);  \
    unsigned ham = ua & 0xFFFF0000u, hbm = ub & 0xFFFF0000u;    \
    float la = (a) - __uint_as_float(ham);                      \
    float lb = (b) - __uint_as_float(hbm);                      \
    HO = (ua >> 16) | hbm;                                      \
    LO = (__float_as_uint(la) >> 16) | (__float_as_uint(lb) & 0xFFFF0000u); \
} while (0)

// ---------------- kernel 0: fp32 -> bf16 hi/lo pre-conversion ----------------
__global__ __launch_bounds__(256)
void k_convert(const float* __restrict__ src, ushort* __restrict__ hi,
               ushort* __restrict__ lo, int n8) {
    int t = blockIdx.x * 256 + threadIdx.x;
    if (t >= n8) return;
    const float4* s = (const float4*)src;
    float4 v0 = s[2 * t], v1 = s[2 * t + 1];
    uint4 hp, lp;
    PK(v0.x, v0.y, hp.x, lp.x);
    PK(v0.z, v0.w, hp.y, lp.y);
    PK(v1.x, v1.y, hp.z, lp.z);
    PK(v1.z, v1.w, hp.w, lp.w);
    ((uint4*)hi)[t] = hp;
    ((uint4*)lo)[t] = lp;
}

// ---------------- kernel 1: code norms + zero accumulators ----------------
__global__ __launch_bounds__(256)
void k_cnorm(const float* __restrict__ cb, float* __restrict__ cnorm,
             double* __restrict__ accum, int* __restrict__ flagc) {
    if (blockIdx.x == 0 && threadIdx.x == 0) { *accum = 0.0; *flagc = 0; }
    const int gid  = blockIdx.x * 256 + threadIdx.x;
    const int code = gid >> 6;
    const int lane = threadIdx.x & 63;
    if (code < KC) {
        float4 v = ((const float4*)cb)[code * D4 + lane];
        float s = v.x*v.x + v.y*v.y + v.z*v.z + v.w*v.w;
        #pragma unroll
        for (int off = 32; off > 0; off >>= 1) s += __shfl_down(s, off);
        if (lane == 0) cnorm[code] = s;
    }
}

// ---------------- kernel 2: 3-term bf16 MFMA GEMM + top-2 argmin (pre-converted) ----------------
__global__ __launch_bounds__(256, 2)
void k_argmin_mfma2(const ushort* __restrict__ zeh, const ushort* __restrict__ zel,
                    const ushort* __restrict__ cbh, const ushort* __restrict__ cbl,
                    const float* __restrict__ cnorm, float4* __restrict__ partial) {
    // 4 tiles of 128 rows x 32 ushorts (8KB each): Ah, Al, Bh, Bl. XOR-swizzled:
    // chunk (row,g) at byte row*64 + ((g ^ ((row>>1)&3))<<4).
    __shared__ __align__(16) char smem[32768];
    char* Ah = smem;
    char* Al = smem + 8192;
    char* Bh = smem + 16384;
    char* Bl = smem + 24576;

    const int tid  = threadIdx.x;
    const int lane = tid & 63;
    const int wid  = tid >> 6;
    const int cl   = lane & 15;
    const int kq   = lane >> 4;
    const int wm   = (wid & 1) * 64;
    const int wn   = (wid >> 1) * 64;
    const int m0   = blockIdx.x * MT;
    const int split = blockIdx.y;

    // staging: this lane fills LDS slot {tid, tid+256}; slot -> (row, swizzled g)
    const int srow = tid >> 2;                       // 0..63 (instr2: +64)
    const int sg   = (tid & 3) ^ ((srow >> 1) & 3);  // unswizzled chunk for this slot
    const unsigned aoff  = (unsigned)(m0 + srow) * 512u + (unsigned)sg * 16u;
    const unsigned boff0 = (unsigned)(split * KSPLIT + srow) * 512u + (unsigned)sg * 16u;
    const int ldsw = wid * 1024;                     // wave-uniform slot base * 16B

    // fragment read offsets (bytes in tile), constant across ks/ch
    int ar[4], br[4];
    #pragma unroll
    for (int mt = 0; mt < 4; ++mt) {
        int r = wm + mt * 16 + cl;
        ar[mt] = r * 64 + ((kq ^ ((r >> 1) & 3)) << 4);
    }
    #pragma unroll
    for (int nt = 0; nt < 4; ++nt) {
        int r = wn + nt * 16 + cl;
        br[nt] = r * 64 + ((kq ^ ((r >> 1) & 3)) << 4);
    }

    float best[16], sec[16]; int bidx[16];
    #pragma unroll
    for (int s = 0; s < 16; ++s) { best[s] = 3.4e38f; sec[s] = 3.4e38f; bidx[s] = 0; }

    for (int ch = 0; ch < NTILES; ++ch) {
        const int c0 = split * KSPLIT + ch * NT;
        const unsigned boff = boff0 + (unsigned)ch * (NT * 512u);
        f32x4 acc[4][4];
        #pragma unroll
        for (int mt = 0; mt < 4; ++mt)
            #pragma unroll
            for (int nt = 0; nt < 4; ++nt)
                acc[mt][nt] = (f32x4){0.f, 0.f, 0.f, 0.f};

        for (int ks = 0; ks < NKS; ++ks) {
            __syncthreads();                       // previous slice's readers done
            const unsigned ka = aoff + (unsigned)(ks << 6);
            const unsigned kb = boff + (unsigned)(ks << 6);
            GLL((const char*)zeh + ka,         Ah + ldsw);
            GLL((const char*)zeh + ka + 32768, Ah + 4096 + ldsw);   // rows 64..127
            GLL((const char*)zel + ka,         Al + ldsw);
            GLL((const char*)zel + ka + 32768, Al + 4096 + ldsw);
            GLL((const char*)cbh + kb,         Bh + ldsw);
            GLL((const char*)cbh + kb + 32768, Bh + 4096 + ldsw);
            GLL((const char*)cbl + kb,         Bl + ldsw);
            GLL((const char*)cbl + kb + 32768, Bl + 4096 + ldsw);
            __syncthreads();                       // barrier drains vmcnt -> LDS valid

            bf16x8 bhf[4], blf[4];
            #pragma unroll
            for (int nt = 0; nt < 4; ++nt) {
                bhf[nt] = *(const bf16x8*)(Bh + br[nt]);
                blf[nt] = *(const bf16x8*)(Bl + br[nt]);
            }
            #pragma unroll
            for (int mt = 0; mt < 4; ++mt) {
                bf16x8 ah = *(const bf16x8*)(Ah + ar[mt]);
                bf16x8 al = *(const bf16x8*)(Al + ar[mt]);
                #pragma unroll
                for (int nt = 0; nt < 4; ++nt) {
                    acc[mt][nt] = __builtin_amdgcn_mfma_f32_16x16x32_bf16(ah, bhf[nt], acc[mt][nt], 0, 0, 0);
                    acc[mt][nt] = __builtin_amdgcn_mfma_f32_16x16x32_bf16(ah, blf[nt], acc[mt][nt], 0, 0, 0);
                    acc[mt][nt] = __builtin_amdgcn_mfma_f32_16x16x32_bf16(al, bhf[nt], acc[mt][nt], 0, 0, 0);
                }
            }
        }
        // fold N-tile into running top-2 (codes ascend: '<' keeps first index)
        #pragma unroll
        for (int nt = 0; nt < 4; ++nt) {
            const int code = c0 + wn + nt * 16 + cl;
            const float cn = cnorm[code];
            #pragma unroll
            for (int mt = 0; mt < 4; ++mt)
                #pragma unroll
                for (int r = 0; r < 4; ++r) {
                    float dist = fmaf(-2.f, acc[mt][nt][r], cn);
                    int s = mt * 4 + r;
                    bool lt = dist < best[s];
                    sec[s] = lt ? best[s] : fminf(sec[s], dist);
                    if (lt) { best[s] = dist; bidx[s] = code; }
                }
        }
    }

    // cross-lane reduce over 16 col-lanes
    #pragma unroll
    for (int m = 1; m < 16; m <<= 1) {
        #pragma unroll
        for (int s = 0; s < 16; ++s) {
            float ob = __shfl_xor(best[s], m);
            int   oi = __shfl_xor(bidx[s], m);
            float os = __shfl_xor(sec[s], m);
            if (ob < best[s] || (ob == best[s] && oi < bidx[s])) {
                sec[s]  = fminf(best[s], os);
                best[s] = ob; bidx[s] = oi;
            } else {
                sec[s]  = fminf(sec[s], ob);
            }
        }
    }
    __syncthreads();
    float* mg = (float*)smem;                 // [2][128][4] floats = 4 KB (reuse LDS)
    if (cl == 0) {
        #pragma unroll
        for (int mt = 0; mt < 4; ++mt)
            #pragma unroll
            for (int r = 0; r < 4; ++r) {
                int row = wm + mt * 16 + kq * 4 + r;
                int o = ((wn >> 6) * 128 + row) * 4;
                mg[o + 0] = best[mt * 4 + r];
                mg[o + 1] = __int_as_float(bidx[mt * 4 + r]);
                mg[o + 2] = sec[mt * 4 + r];
            }
    }
    __syncthreads();
    if (tid < MT) {
        float b0 = mg[tid * 4],         s0v = mg[tid * 4 + 2];
        int   i0 = __float_as_int(mg[tid * 4 + 1]);
        float b1 = mg[(128 + tid) * 4], s1v = mg[(128 + tid) * 4 + 2];
        int   i1 = __float_as_int(mg[(128 + tid) * 4 + 1]);
        float B, S; int I;
        if (b1 < b0 || (b1 == b0 && i1 < i0)) { B = b1; I = i1; S = fminf(s1v, b0); }
        else                                   { B = b0; I = i0; S = fminf(s0v, b1); }
        partial[(size_t)split * N_TOK + m0 + tid] = make_float4(B, __int_as_float(I), S, 0.f);
    }
}

// ---------------- fallback: R2 kernel (in-loop conversion), 16 splits ----------------
#define ASTR 40
__device__ __forceinline__ void stage8(const float* __restrict__ gp,
                                       ushort* __restrict__ h, ushort* __restrict__ l) {
    float4 v0 = *(const float4*)gp;
    float4 v1 = *(const float4*)(gp + 4);
    uint4 hp, lp;
    PK(v0.x, v0.y, hp.x, lp.x);
    PK(v0.z, v0.w, hp.y, lp.y);
    PK(v1.x, v1.y, hp.z, lp.z);
    PK(v1.z, v1.w, hp.w, lp.w);
    *(uint4*)h = hp;
    *(uint4*)l = lp;
}

__global__ __launch_bounds__(256, 2)
void k_argmin_fb(const float* __restrict__ ze, const float* __restrict__ cb,
                 const float* __restrict__ cnorm, float4* __restrict__ partial) {
    __shared__ ushort smem[4 * 128 * ASTR];
    ushort* Ah = smem;
    ushort* Al = smem + 128 * ASTR;
    ushort* Bh = smem + 2 * 128 * ASTR;
    ushort* Bl = smem + 3 * 128 * ASTR;

    const int tid  = threadIdx.x;
    const int lane = tid & 63;
    const int wid  = tid >> 6;
    const int cl   = lane & 15;
    const int kq   = lane >> 4;
    const int wm   = (wid & 1) * 64;
    const int wn   = (wid >> 1) * 64;
    const int m0   = blockIdx.x * MT;
    const int split = blockIdx.y;

    const int r0 = tid >> 2;
    const int g0 = (tid & 3) * 8;
    const float* zeA = ze + (size_t)(m0 + r0) * DD + g0;
    ushort* lAh0 = Ah + r0 * ASTR + g0;
    ushort* lAl0 = Al + r0 * ASTR + g0;
    ushort* lAh1 = Ah + (r0 + 64) * ASTR + g0;
    ushort* lAl1 = Al + (r0 + 64) * ASTR + g0;
    ushort* lBh0 = Bh + r0 * ASTR + g0;
    ushort* lBl0 = Bl + r0 * ASTR + g0;
    ushort* lBh1 = Bh + (r0 + 64) * ASTR + g0;
    ushort* lBl1 = Bl + (r0 + 64) * ASTR + g0;

    const int aoff = (wm + cl) * ASTR + kq * 8;
    const int boff = (wn + cl) * ASTR + kq * 8;

    float best[16], sec[16]; int bidx[16];
    #pragma unroll
    for (int s = 0; s < 16; ++s) { best[s] = 3.4e38f; sec[s] = 3.4e38f; bidx[s] = 0; }

    for (int ch = 0; ch < 4; ++ch) {
        const int c0 = split * 512 + ch * NT;
        const float* cbB = cb + (size_t)(c0 + r0) * DD + g0;
        f32x4 acc[4][4];
        #pragma unroll
        for (int mt = 0; mt < 4; ++mt)
            #pragma unroll
            for (int nt = 0; nt < 4; ++nt)
                acc[mt][nt] = (f32x4){0.f, 0.f, 0.f, 0.f};

        for (int ks = 0; ks < NKS; ++ks) {
            __syncthreads();
            stage8(zeA + ks * BK,           lAh0, lAl0);
            stage8(zeA + 64 * DD + ks * BK, lAh1, lAl1);
            stage8(cbB + ks * BK,           lBh0, lBl0);
            stage8(cbB + 64 * DD + ks * BK, lBh1, lBl1);
            __syncthreads();

            bf16x8 bh[4], bl[4];
            #pragma unroll
            for (int nt = 0; nt < 4; ++nt) {
                bh[nt] = *(const bf16x8*)(Bh + boff + nt * 16 * ASTR);
                bl[nt] = *(const bf16x8*)(Bl + boff + nt * 16 * ASTR);
            }
            #pragma unroll
            for (int mt = 0; mt < 4; ++mt) {
                bf16x8 ah = *(const bf16x8*)(Ah + aoff + mt * 16 * ASTR);
                bf16x8 al = *(const bf16x8*)(Al + aoff + mt * 16 * ASTR);
                #pragma unroll
                for (int nt = 0; nt < 4; ++nt) {
                    acc[mt][nt] = __builtin_amdgcn_mfma_f32_16x16x32_bf16(ah, bh[nt], acc[mt][nt], 0, 0, 0);
                    acc[mt][nt] = __builtin_amdgcn_mfma_f32_16x16x32_bf16(ah, bl[nt], acc[mt][nt], 0, 0, 0);
                    acc[mt][nt] = __builtin_amdgcn_mfma_f32_16x16x32_bf16(al, bh[nt], acc[mt][nt], 0, 0, 0);
                }
            }
        }
        #pragma unroll
        for (int nt = 0; nt < 4; ++nt) {
            const int code = c0 + wn + nt * 16 + cl;
            const float cn = cnorm[code];
            #pragma unroll
            for (int mt = 0; mt < 4; ++mt)
                #pragma unroll
                for (int r = 0; r < 4; ++r) {
                    float dist = fmaf(-2.f, acc[mt][nt][r], cn);
                    int s = mt * 4 + r;
                    bool lt = dist < best[s];
                    sec[s] = lt ? best[s] : fminf(sec[s], dist);
                    if (lt) { best[s] = dist; bidx[s] = code; }
                }
        }
    }

    #pragma unroll
    for (int m = 1; m < 16; m <<= 1) {
        #pragma unroll
        for (int s = 0; s < 16; ++s) {
            float ob = __shfl_xor(best[s], m);
            int   oi = __shfl_xor(bidx[s], m);
            float os = __shfl_xor(sec[s], m);
            if (ob < best[s] || (ob == best[s] && oi < bidx[s])) {
                sec[s]  = fminf(best[s], os);
                best[s] = ob; bidx[s] = oi;
            } else {
                sec[s]  = fminf(sec[s], ob);
            }
        }
    }
    __syncthreads();
    float* mg = (float*)smem;
    if (cl == 0) {
        #pragma unroll
        for (int mt = 0; mt < 4; ++mt)
            #pragma unroll
            for (int r = 0; r < 4; ++r) {
                int row = wm + mt * 16 + kq * 4 + r;
                int o = ((wn >> 6) * 128 + row) * 4;
                mg[o + 0] = best[mt * 4 + r];
                mg[o + 1] = __int_as_float(bidx[mt * 4 + r]);
                mg[o + 2] = sec[mt * 4 + r];
            }
    }
    __syncthreads();
    if (tid < MT) {
        float b0 = mg[tid * 4],         s0v = mg[tid * 4 + 2];
        int   i0 = __float_as_int(mg[tid * 4 + 1]);
        float b1 = mg[(128 + tid) * 4], s1v = mg[(128 + tid) * 4 + 2];
        int   i1 = __float_as_int(mg[(128 + tid) * 4 + 1]);
        float B, S; int I;
        if (b1 < b0 || (b1 == b0 && i1 < i0)) { B = b1; I = i1; S = fminf(s1v, b0); }
        else                                   { B = b0; I = i0; S = fminf(s0v, b1); }
        partial[(size_t)split * N_TOK + m0 + tid] = make_float4(B, __int_as_float(I), S, 0.f);
    }
}

// ---------------- kernel 3: combine splits, emit idx + rescore flags ----------------
__global__ __launch_bounds__(256)
void k_combine(const float4* __restrict__ partial, int* __restrict__ idxi,
               float* __restrict__ idxf, int* __restrict__ flagc,
               int* __restrict__ flag_list, int splits) {
    const int t = blockIdx.x * 256 + threadIdx.x;
    float B = 3.4e38f, S = 3.4e38f; int I = 0;
    for (int s = 0; s < splits; ++s) {
        float4 p = partial[(size_t)s * N_TOK + t];
        int oi = __float_as_int(p.y);
        if (p.x < B || (p.x == B && oi < I)) { S = fminf(B, p.z); B = p.x; I = oi; }
        else                                  { S = fminf(S, p.x); }
    }
    idxi[t] = I;
    idxf[t] = (float)I;
    if (S - B < EPS_GAP) {
        int pos = atomicAdd(flagc, 1);
        if (pos < FLAG_CAP) flag_list[pos] = t;
    }
}

// ---------------- kernel 4: exact fp32 rescore for flagged tokens ----------------
__global__ __launch_bounds__(256)
void k_rescore(const float* __restrict__ ze, const float* __restrict__ cb,
               const float* __restrict__ cnorm, const int* __restrict__ flagc,
               const int* __restrict__ flag_list, int* __restrict__ idxi,
               float* __restrict__ idxf) {
    __shared__ float xsh[DD];
    __shared__ float2 red[256];
    const int tid = threadIdx.x;
    int nf = flagc[0]; if (nf > FLAG_CAP) nf = FLAG_CAP;
    for (int f = blockIdx.x; f < nf; f += gridDim.x) {
        const int t = flag_list[f];
        if (tid < 64) *(float4*)&xsh[tid * 4] = ((const float4*)ze)[(size_t)t * D4 + tid];
        __syncthreads();
        float B = 3.4e38f; int I = 0;
        for (int c = tid; c < KC; c += 256) {
            const float4* cr = (const float4*)(cb + (size_t)c * DD);
            float dot = 0.f;
            #pragma unroll 8
            for (int j = 0; j < D4; ++j) {
                float4 cv = cr[j];
                float4 xv = *(const float4*)&xsh[j * 4];
                dot = fmaf(cv.x, xv.x, dot);
                dot = fmaf(cv.y, xv.y, dot);
                dot = fmaf(cv.z, xv.z, dot);
                dot = fmaf(cv.w, xv.w, dot);
            }
            float dist = fmaf(-2.f, dot, cnorm[c]);
            if (dist < B) { B = dist; I = c; }
        }
        red[tid] = make_float2(B, __int_as_float(I));
        __syncthreads();
        for (int s = 128; s > 0; s >>= 1) {
            if (tid < s) {
                float2 o = red[tid + s], me = red[tid];
                int oi = __float_as_int(o.y), mi = __float_as_int(me.y);
                if (o.x < me.x || (o.x == me.x && oi < mi)) red[tid] = o;
            }
            __syncthreads();
        }
        if (tid == 0) { int I2 = __float_as_int(red[0].y); idxi[t] = I2; idxf[t] = (float)I2; }
        __syncthreads();
    }
}

// ---------------- kernel 5: gather + STE output + loss partial ----------------
__global__ __launch_bounds__(256)
void k_gather(const float* __restrict__ ze, const float* __restrict__ cb,
              const int* __restrict__ idxi, float* __restrict__ zq,
              double* __restrict__ accum) {
    const int tid = threadIdx.x;
    const int t0  = blockIdx.x * 16;
    double dsum = 0.0;
    #pragma unroll
    for (int i = 0; i < 4; ++i) {
        int f = tid + i * 256;
        int row = f >> 6, e = f & 63;
        int t = t0 + row;
        int code = idxi[t];
        float4 zev = ((const float4*)ze)[(size_t)t * D4 + e];
        float4 cbv = ((const float4*)cb)[(size_t)code * D4 + e];
        float dx = cbv.x - zev.x, dy = cbv.y - zev.y;
        float dz = cbv.z - zev.z, dw = cbv.w - zev.w;
        float4 o;
        o.x = zev.x + dx; o.y = zev.y + dy; o.z = zev.z + dz; o.w = zev.w + dw;
        ((float4*)zq)[(size_t)t * D4 + e] = o;
        dsum += (double)dx * dx + (double)dy * dy + (double)dz * dz + (double)dw * dw;
    }
    #pragma unroll
    for (int off = 32; off > 0; off >>= 1) dsum += __shfl_down(dsum, off);
    __shared__ double wsum[4];
    if ((tid & 63) == 0) wsum[tid >> 6] = dsum;
    __syncthreads();
    if (tid == 0) atomicAdd(accum, wsum[0] + wsum[1] + wsum[2] + wsum[3]);
}

// ---------------- kernel 6: finalize loss ----------------
__global__ void k_final(const double* __restrict__ accum, float* __restrict__ loss) {
    loss[0] = (float)(accum[0] * (1.25 / 8388608.0));
}

extern "C" void kernel_launch(void* const* d_in, const int* in_sizes, int n_in,
                              void* d_out, int out_size, void* d_ws, size_t ws_size,
                              hipStream_t stream) {
    const float* ze = (const float*)d_in[0];
    const float* cb = (const float*)d_in[1];

    float* out      = (float*)d_out;
    float* out_zq   = out;
    float* out_idx  = out + (size_t)N_TOK * DD;
    float* out_loss = out_idx + N_TOK;

    char*   ws    = (char*)d_ws;
    float*  cnorm = (float*)ws;                     // 32 KB
    int*    idxi  = (int*)(ws + 32768);             // 128 KB
    double* accum = (double*)(ws + 163840);         // 8 B
    int*    flagc = (int*)(ws + 163848);            // 4 B

    // full-path ws layout
    const size_t OFF_FLAGL = 163856;                          // 64 KB
    const size_t OFF_ZEH   = 229632;                          // 16 MB
    const size_t OFF_ZEL   = OFF_ZEH + (size_t)N_TOK * DD * 2;
    const size_t OFF_CBH   = OFF_ZEL + (size_t)N_TOK * DD * 2;
    const size_t OFF_CBL   = OFF_CBH + (size_t)KC * DD * 2;
    const size_t OFF_PART  = OFF_CBL + (size_t)KC * DD * 2;
    const size_t NEED_FULL = OFF_PART + (size_t)SPLITS * N_TOK * 16;   // ~46.4 MB

    hipLaunchKernelGGL(k_cnorm, dim3(KC / 4), dim3(256), 0, stream, cb, cnorm, accum, flagc);

    if (ws_size >= NEED_FULL) {
        int*    flag_list = (int*)(ws + OFF_FLAGL);
        ushort* zeh = (ushort*)(ws + OFF_ZEH);
        ushort* zel = (ushort*)(ws + OFF_ZEL);
        ushort* cbh = (ushort*)(ws + OFF_CBH);
        ushort* cbl = (ushort*)(ws + OFF_CBL);
        float4* partial = (float4*)(ws + OFF_PART);

        hipLaunchKernelGGL(k_convert, dim3(N_TOK * DD / 8 / 256), dim3(256), 0, stream, ze, zeh, zel, N_TOK * DD / 8);
        hipLaunchKernelGGL(k_convert, dim3(KC * DD / 8 / 256),    dim3(256), 0, stream, cb, cbh, cbl, KC * DD / 8);
        hipLaunchKernelGGL(k_argmin_mfma2, dim3(N_TOK / MT, SPLITS), dim3(256), 0, stream,
                           zeh, zel, cbh, cbl, cnorm, partial);
        hipLaunchKernelGGL(k_combine, dim3(N_TOK / 256), dim3(256), 0, stream,
                           partial, idxi, out_idx, flagc, flag_list, SPLITS);
    } else {
        // fallback: R2 path (in-kernel conversion, 16 splits)
        const size_t big_off = 163856;
        const size_t need2 = big_off + (size_t)FLAG_CAP * 4 + 16ull * N_TOK * 16;
        int* flag_list; float4* partial;
        if (ws_size >= need2) {
            flag_list = (int*)(ws + big_off);
            partial   = (float4*)(ws + big_off + (size_t)FLAG_CAP * 4);
        } else {
            partial   = (float4*)d_out;
            flag_list = (int*)((char*)d_out + 16ull * N_TOK * 16);
        }
        hipLaunchKernelGGL(k_argmin_fb, dim3(N_TOK / MT, 16), dim3(256), 0, stream, ze, cb, cnorm, partial);
        hipLaunchKernelGGL(k_combine, dim3(N_TOK / 256), dim3(256), 0, stream,
                           partial, idxi, out_idx, flagc, flag_list, 16);
        // rescore/gather below are path-independent, but flag_list differs:
        hipLaunchKernelGGL(k_rescore, dim3(128), dim3(256), 0, stream, ze, cb, cnorm, flagc, flag_list, idxi, out_idx);
        hipLaunchKernelGGL(k_gather,  dim3(N_TOK / 16), dim3(256), 0, stream, ze, cb, idxi, out_zq, accum);
        hipLaunchKernelGGL(k_final,   dim3(1), dim3(1), 0, stream, accum, out_loss);
        return;
    }

    int* flag_list = (int*)(ws + OFF_FLAGL);
    hipLaunchKernelGGL(k_rescore, dim3(128), dim3(256), 0, stream, ze, cb, cnorm, flagc, flag_list, idxi, out_idx);
    hipLaunchKernelGGL(k_gather,  dim3(N_TOK / 16), dim3(256), 0, stream, ze, cb, idxi, out_zq, accum);
    hipLaunchKernelGGL(k_final,   dim3(1), dim3(1), 0, stream, accum, out_loss);
}